// Round 4
// baseline (673.775 us; speedup 1.0000x reference)
//
#include <hip/hip_runtime.h>

#define D 64
#define NBLK 256          // edge-chunk blocks for hist/scatter
#define NB_MAX 1024       // max buckets (nodes/64) supported by LDS arrays
#define SCAN_CHUNK 1024

// ============================================================================
// Atomic-free CSR-by-bucket path
//   bucket = dst >> 6  (64 nodes per bucket)
//   pairs[pos] = (local_dst << 16) | src   (requires n_nodes <= 65536)
// ============================================================================

// Per-block bucket histogram (LDS atomics only) -> cnt[bucket*NBLK + blk]
__global__ void bhist_kernel(const int* __restrict__ dst, int* __restrict__ cnt,
                             int n_edges, int nb, int chunk) {
    __shared__ int hist[NB_MAX];
    int blk = blockIdx.x, tid = threadIdx.x;
    for (int i = tid; i < nb; i += 256) hist[i] = 0;
    __syncthreads();
    int e0 = blk * chunk;
    int e1 = e0 + chunk; if (e1 > n_edges) e1 = n_edges;
    for (int e = e0 + tid; e < e1; e += 256) atomicAdd(&hist[dst[e] >> 6], 1);
    __syncthreads();
    for (int i = tid; i < nb; i += 256) cnt[i * NBLK + blk] = hist[i];
}

// One block per bucket: exclusive scan of its 256 block-counts.
// base[bucket*NBLK + blk] = excl prefix; bucket_total[bucket] = sum.
__global__ void scan_cnt_kernel(const int* __restrict__ cnt, int* __restrict__ base,
                                int* __restrict__ bucket_total) {
    __shared__ int wsum[4];
    int bkt = blockIdx.x, tid = threadIdx.x;
    int v = cnt[bkt * NBLK + tid];
    int lane = tid & 63, w = tid >> 6;
    int x = v;
    for (int o = 1; o < 64; o <<= 1) {
        int y = __shfl_up(x, o, 64);
        if (lane >= o) x += y;
    }
    if (lane == 63) wsum[w] = x;
    __syncthreads();
    int pre = 0;
    for (int i = 0; i < w; ++i) pre += wsum[i];
    int excl = x - v + pre;
    base[bkt * NBLK + tid] = excl;
    if (tid == 255) bucket_total[bkt] = excl + v;
}

// Single wave: exclusive scan of bucket totals -> boff[0..nb], boff[nb]=E.
__global__ void scan_buckets_kernel(const int* __restrict__ totals,
                                    int* __restrict__ boff, int nb) {
    int lane = threadIdx.x;
    int carry = 0;
    for (int s = 0; s < nb; s += 64) {
        int i = s + lane;
        int v = (i < nb) ? totals[i] : 0;
        int x = v;
        for (int o = 1; o < 64; o <<= 1) {
            int y = __shfl_up(x, o, 64);
            if (lane >= o) x += y;
        }
        if (i < nb) boff[i] = carry + x - v;
        carry += __shfl(x, 63, 64);
    }
    if (lane == 0) boff[nb] = carry;
}

// Re-read chunk; place packed (local_dst,src) into pre-reserved contiguous
// ranges using LDS cursors only. No global atomics.
__global__ void scatter_kernel(const int* __restrict__ src, const int* __restrict__ dst,
                               const int* __restrict__ base, const int* __restrict__ boff,
                               unsigned* __restrict__ pairs,
                               int n_edges, int nb, int chunk) {
    __shared__ int cursor[NB_MAX];
    int blk = blockIdx.x, tid = threadIdx.x;
    for (int i = tid; i < nb; i += 256) cursor[i] = boff[i] + base[i * NBLK + blk];
    __syncthreads();
    int e0 = blk * chunk;
    int e1 = e0 + chunk; if (e1 > n_edges) e1 = n_edges;
    for (int e = e0 + tid; e < e1; e += 256) {
        int d = dst[e], s = src[e];
        int bkt = d >> 6;
        int pos = atomicAdd(&cursor[bkt], 1);   // LDS atomic
        pairs[pos] = ((unsigned)(d & 63) << 16) | (unsigned)s;
    }
}

// One block per bucket: accumulate gathered feature rows into a 64x64 LDS
// accumulator (wave-per-edge, ds_add_f32), then apply W^T + bias and store.
__global__ void agg_kernel(const float* __restrict__ feature,
                           const unsigned* __restrict__ pairs,
                           const int* __restrict__ boff,
                           const float* __restrict__ W,
                           const float* __restrict__ bias,
                           float* __restrict__ out, int n_nodes) {
    __shared__ float acc[64 * 64];   // acc[local_dst*64 + dim]
    __shared__ float Wt[64 * 65];    // Wt[k*65 + o] = W[o*64 + k]
    int tid = threadIdx.x;
    for (int i = tid; i < 64 * 64; i += 256) {
        acc[i] = 0.f;
        int o = i >> 6, k = i & 63;
        Wt[k * 65 + o] = W[i];
    }
    __syncthreads();

    int bkt = blockIdx.x;
    int lane = tid & 63, w = tid >> 6;
    int e0 = boff[bkt], e1 = boff[bkt + 1];

    for (int s = e0 + w * 64; s < e1; s += 256) {
        int m = e1 - s; if (m > 64) m = 64;
        unsigned p = (lane < m) ? pairs[s + lane] : 0u;
        int j = 0;
        for (; j + 4 <= m; j += 4) {
            unsigned p0 = __shfl(p, j + 0, 64);
            unsigned p1 = __shfl(p, j + 1, 64);
            unsigned p2 = __shfl(p, j + 2, 64);
            unsigned p3 = __shfl(p, j + 3, 64);
            float f0 = feature[(p0 & 0xffffu) * D + lane];
            float f1 = feature[(p1 & 0xffffu) * D + lane];
            float f2 = feature[(p2 & 0xffffu) * D + lane];
            float f3 = feature[(p3 & 0xffffu) * D + lane];
            atomicAdd(&acc[(p0 >> 16) * 64 + lane], f0);
            atomicAdd(&acc[(p1 >> 16) * 64 + lane], f1);
            atomicAdd(&acc[(p2 >> 16) * 64 + lane], f2);
            atomicAdd(&acc[(p3 >> 16) * 64 + lane], f3);
        }
        for (; j < m; ++j) {
            unsigned pj = __shfl(p, j, 64);
            atomicAdd(&acc[(pj >> 16) * 64 + lane], feature[(pj & 0xffffu) * D + lane]);
        }
    }
    __syncthreads();

    int n0 = bkt * 64;
    for (int ln = w; ln < 64; ln += 4) {
        int n = n0 + ln;
        if (n >= n_nodes) break;
        float r = bias[lane];
#pragma unroll
        for (int k = 0; k < 64; ++k) r += acc[ln * 64 + k] * Wt[k * 65 + lane];
        out[n * D + lane] = r;
    }
}

// ============================================================================
// Fallback paths (proven in earlier rounds)
// ============================================================================

__global__ void hist_kernel(const int* __restrict__ dst, int* __restrict__ counts, int n_edges) {
    int e = blockIdx.x * blockDim.x + threadIdx.x;
    if (e < n_edges) atomicAdd(&counts[dst[e]], 1);
}

__global__ void reduce_kernel(const int* __restrict__ counts, int* __restrict__ partials, int n_nodes) {
    __shared__ int wsums[4];
    int tid = threadIdx.x;
    int base = blockIdx.x * SCAN_CHUNK + tid * 4;
    int s = 0;
#pragma unroll
    for (int i = 0; i < 4; ++i) {
        int idx = base + i;
        if (idx < n_nodes) s += counts[idx];
    }
    for (int o = 32; o > 0; o >>= 1) s += __shfl_down(s, o, 64);
    int lane = tid & 63, wave = tid >> 6;
    if (lane == 0) wsums[wave] = s;
    __syncthreads();
    if (tid == 0) partials[blockIdx.x] = wsums[0] + wsums[1] + wsums[2] + wsums[3];
}

__global__ void scan_partials_kernel(const int* __restrict__ partials, int* __restrict__ pscan, int nblk) {
    int lane = threadIdx.x;
    int v = (lane < nblk) ? partials[lane] : 0;
    int orig = v;
    for (int o = 1; o < 64; o <<= 1) {
        int y = __shfl_up(v, o, 64);
        if (lane >= o) v += y;
    }
    if (lane < nblk) pscan[lane] = v - orig;
}

__global__ void scan_kernel(const int* __restrict__ counts, const int* __restrict__ pscan,
                            int* __restrict__ offsets, int* __restrict__ cursors, int n_nodes) {
    __shared__ int wsums[4];
    int tid = threadIdx.x;
    int base = blockIdx.x * SCAN_CHUNK + tid * 4;
    int c[4];
    int tsum = 0;
#pragma unroll
    for (int i = 0; i < 4; ++i) {
        int idx = base + i;
        c[i] = (idx < n_nodes) ? counts[idx] : 0;
        tsum += c[i];
    }
    int lane = tid & 63, wave = tid >> 6;
    int x = tsum;
    for (int o = 1; o < 64; o <<= 1) {
        int y = __shfl_up(x, o, 64);
        if (lane >= o) x += y;
    }
    if (lane == 63) wsums[wave] = x;
    __syncthreads();
    int wpre = 0;
    for (int w = 0; w < wave; ++w) wpre += wsums[w];
    int excl = (x - tsum) + wpre + pscan[blockIdx.x];
#pragma unroll
    for (int i = 0; i < 4; ++i) {
        int idx = base + i;
        if (idx < n_nodes) { offsets[idx] = excl; cursors[idx] = excl; }
        excl += c[i];
    }
}

__global__ void fill_kernel(const int* __restrict__ src, const int* __restrict__ dst,
                            int* __restrict__ cursors, int* __restrict__ elist, int n_edges) {
    int e = blockIdx.x * blockDim.x + threadIdx.x;
    if (e < n_edges) {
        int pos = atomicAdd(&cursors[dst[e]], 1);
        elist[pos] = src[e];
    }
}

__global__ void agg_linear_kernel(const float* __restrict__ feature,
                                  const int* __restrict__ elist,
                                  const int* __restrict__ offsets,
                                  const int* __restrict__ counts,
                                  const float* __restrict__ W,
                                  const float* __restrict__ b,
                                  float* __restrict__ out,
                                  int n_nodes, int total_waves) {
    __shared__ float Wt[64 * 65];
    int tid = threadIdx.x;
    for (int i = tid; i < 64 * 64; i += 256) {
        int o = i >> 6, k = i & 63;
        Wt[k * 65 + o] = W[i];
    }
    __syncthreads();
    int lane = tid & 63;
    int waveId = (blockIdx.x * 256 + tid) >> 6;
    float bias = b[lane];
    for (int n = waveId; n < n_nodes; n += total_waves) {
        int off = offsets[n];
        int deg = counts[n];
        float acc = 0.f;
        int j = 0;
        for (; j + 4 <= deg; j += 4) {
            int s0 = elist[off + j + 0];
            int s1 = elist[off + j + 1];
            int s2 = elist[off + j + 2];
            int s3 = elist[off + j + 3];
            acc += feature[s0 * D + lane] + feature[s1 * D + lane]
                 + feature[s2 * D + lane] + feature[s3 * D + lane];
        }
        for (; j < deg; ++j) acc += feature[elist[off + j] * D + lane];
        float r = bias;
#pragma unroll
        for (int k = 0; k < 64; ++k) r += __shfl(acc, k, 64) * Wt[k * 65 + lane];
        out[n * D + lane] = r;
    }
}

__global__ void gcn_scatter_kernel(const float* __restrict__ feature,
                                   const int* __restrict__ src,
                                   const int* __restrict__ dst,
                                   float* __restrict__ out,
                                   int n_edges) {
    int e = blockIdx.x * 4 + (threadIdx.x >> 6);
    int lane = threadIdx.x & 63;
    if (e < n_edges) atomicAdd(&out[dst[e] * D + lane], feature[src[e] * D + lane]);
}

__global__ void gcn_linear_kernel(float* __restrict__ out,
                                  const float* __restrict__ W,
                                  const float* __restrict__ b,
                                  int n_nodes) {
    __shared__ float Wt[64 * 65];
    int tid = threadIdx.x;
    for (int i = tid; i < 64 * 64; i += 256) {
        int o = i >> 6, k = i & 63;
        Wt[k * 65 + o] = W[i];
    }
    __syncthreads();
    int lane = tid & 63;
    int n = blockIdx.x * 4 + (tid >> 6);
    if (n >= n_nodes) return;
    float val = out[n * D + lane];
    float acc = b[lane];
#pragma unroll
    for (int k = 0; k < 64; ++k) acc += __shfl(val, k, 64) * Wt[k * 65 + lane];
    out[n * D + lane] = acc;
}

// ============================================================================

extern "C" void kernel_launch(void* const* d_in, const int* in_sizes, int n_in,
                              void* d_out, int out_size, void* d_ws, size_t ws_size,
                              hipStream_t stream) {
    const float* feature = (const float*)d_in[0];
    const int* src       = (const int*)d_in[1];
    const int* dst       = (const int*)d_in[2];
    const float* W       = (const float*)d_in[3];
    const float* b       = (const float*)d_in[4];
    float* out           = (float*)d_out;

    int n_edges = in_sizes[1];
    int n_nodes = in_sizes[0] / D;

    int nb = (n_nodes + 63) >> 6;                          // buckets of 64 nodes
    int chunk = (n_edges + NBLK - 1) / NBLK;

    // Atomic-free path workspace (ints):
    // cnt[nb*NBLK] | base[nb*NBLK] | btotal[nb] | boff[nb+1] | pairs[E]
    size_t needNew = ((size_t)2 * nb * NBLK + 2 * nb + 1 + (size_t)n_edges) * sizeof(int);

    if (n_nodes <= 65536 && nb <= NB_MAX && ws_size >= needNew) {
        int* cnt      = (int*)d_ws;
        int* base     = cnt + (size_t)nb * NBLK;
        int* btotal   = base + (size_t)nb * NBLK;
        int* boff     = btotal + nb;
        unsigned* pairs = (unsigned*)(boff + nb + 1);

        bhist_kernel<<<NBLK, 256, 0, stream>>>(dst, cnt, n_edges, nb, chunk);
        scan_cnt_kernel<<<nb, 256, 0, stream>>>(cnt, base, btotal);
        scan_buckets_kernel<<<1, 64, 0, stream>>>(btotal, boff, nb);
        scatter_kernel<<<NBLK, 256, 0, stream>>>(src, dst, base, boff, pairs,
                                                 n_edges, nb, chunk);
        agg_kernel<<<nb, 256, 0, stream>>>(feature, pairs, boff, W, b, out, n_nodes);
        return;
    }

    // Tier B fallback (round-2 path)
    size_t needB = ((size_t)3 * n_nodes + 128 + (size_t)n_edges) * sizeof(int);
    int nblk_scan = (n_nodes + SCAN_CHUNK - 1) / SCAN_CHUNK;
    if (ws_size >= needB && nblk_scan <= 64) {
        int* counts   = (int*)d_ws;
        int* offsets  = counts + n_nodes;
        int* cursors  = offsets + n_nodes;
        int* partials = cursors + n_nodes;
        int* pscan    = partials + 64;
        int* elist    = pscan + 64;

        hipMemsetAsync(counts, 0, (size_t)n_nodes * sizeof(int), stream);
        hist_kernel<<<(n_edges + 255) / 256, 256, 0, stream>>>(dst, counts, n_edges);
        reduce_kernel<<<nblk_scan, 256, 0, stream>>>(counts, partials, n_nodes);
        scan_partials_kernel<<<1, 64, 0, stream>>>(partials, pscan, nblk_scan);
        scan_kernel<<<nblk_scan, 256, 0, stream>>>(counts, pscan, offsets, cursors, n_nodes);
        fill_kernel<<<(n_edges + 255) / 256, 256, 0, stream>>>(src, dst, cursors, elist, n_edges);
        agg_linear_kernel<<<3125, 256, 0, stream>>>(feature, elist, offsets, counts, W, b, out,
                                                    n_nodes, 3125 * 4);
        return;
    }

    // Last resort (round-1 path)
    hipMemsetAsync(d_out, 0, (size_t)out_size * sizeof(float), stream);
    gcn_scatter_kernel<<<(n_edges + 3) / 4, 256, 0, stream>>>(feature, src, dst, out, n_edges);
    gcn_linear_kernel<<<(n_nodes + 3) / 4, 256, 0, stream>>>(out, W, b, n_nodes);
}

// Round 5
// 207.648 us; speedup vs baseline: 3.2448x; 3.2448x over previous
//
#include <hip/hip_runtime.h>

#define D 64
#define NBLK 512          // edge-chunk blocks for bhist/scatter (2 blocks/CU)
#define NB_MAX 1024       // max buckets (nodes/64) for LDS hist/cursor arrays
#define CAP 2048          // per-chunk sorted-edge capacity in agg LDS
#define SCAN_CHUNK 1024

// ============================================================================
// Atomic-free bucket path:
//   bucket = dst >> 6  (64 nodes/bucket); pairs[pos] = (local_dst<<16) | src
//   (requires n_nodes <= 65536)
// ============================================================================

// Per-block bucket histogram (LDS atomics only) -> cnt[bucket*NBLK + blk]
__global__ void bhist_kernel(const int* __restrict__ dst, int* __restrict__ cnt,
                             int n_edges, int nb, int chunk) {
    __shared__ int hist[NB_MAX];
    int blk = blockIdx.x, tid = threadIdx.x;
    for (int i = tid; i < nb; i += 256) hist[i] = 0;
    __syncthreads();
    int e0 = blk * chunk;
    int e1 = e0 + chunk; if (e1 > n_edges) e1 = n_edges;
    for (int e = e0 + tid; e < e1; e += 256) atomicAdd(&hist[dst[e] >> 6], 1);
    __syncthreads();
    for (int i = tid; i < nb; i += 256) cnt[i * NBLK + blk] = hist[i];
}

// One block per bucket: exclusive scan of its NBLK block-counts (2 per thread).
__global__ void scan_cnt_kernel(const int* __restrict__ cnt, int* __restrict__ base,
                                int* __restrict__ bucket_total) {
    __shared__ int wsum[4];
    int bkt = blockIdx.x, tid = threadIdx.x;
    int c0 = cnt[bkt * NBLK + tid * 2 + 0];
    int c1 = cnt[bkt * NBLK + tid * 2 + 1];
    int t = c0 + c1;
    int lane = tid & 63, w = tid >> 6;
    int x = t;
    for (int o = 1; o < 64; o <<= 1) {
        int y = __shfl_up(x, o, 64);
        if (lane >= o) x += y;
    }
    if (lane == 63) wsum[w] = x;
    __syncthreads();
    int pre = 0;
    for (int i = 0; i < w; ++i) pre += wsum[i];
    int excl = x - t + pre;
    base[bkt * NBLK + tid * 2 + 0] = excl;
    base[bkt * NBLK + tid * 2 + 1] = excl + c0;
    if (tid == 255) bucket_total[bkt] = excl + t;
}

// Single wave: exclusive scan of bucket totals -> boff[0..nb], boff[nb]=E.
__global__ void scan_buckets_kernel(const int* __restrict__ totals,
                                    int* __restrict__ boff, int nb) {
    int lane = threadIdx.x;
    int carry = 0;
    for (int s = 0; s < nb; s += 64) {
        int i = s + lane;
        int v = (i < nb) ? totals[i] : 0;
        int x = v;
        for (int o = 1; o < 64; o <<= 1) {
            int y = __shfl_up(x, o, 64);
            if (lane >= o) x += y;
        }
        if (i < nb) boff[i] = carry + x - v;
        carry += __shfl(x, 63, 64);
    }
    if (lane == 0) boff[nb] = carry;
}

// Place packed pairs into pre-reserved contiguous bucket ranges. LDS cursors only.
__global__ void scatter_kernel(const int* __restrict__ src, const int* __restrict__ dst,
                               const int* __restrict__ base, const int* __restrict__ boff,
                               unsigned* __restrict__ pairs,
                               int n_edges, int nb, int chunk) {
    __shared__ int cursor[NB_MAX];
    int blk = blockIdx.x, tid = threadIdx.x;
    for (int i = tid; i < nb; i += 256) cursor[i] = boff[i] + base[i * NBLK + blk];
    __syncthreads();
    int e0 = blk * chunk;
    int e1 = e0 + chunk; if (e1 > n_edges) e1 = n_edges;
    for (int e = e0 + tid; e < e1; e += 256) {
        int d = dst[e], s = src[e];
        int pos = atomicAdd(&cursor[d >> 6], 1);   // LDS atomic
        pairs[pos] = ((unsigned)(d & 63) << 16) | (unsigned)s;
    }
}

// One 1024-thread block per bucket: in-LDS counting sort by local dst, then
// wave-per-node register-accumulator gather + fused W^T/bias epilogue.
__global__ void __launch_bounds__(1024)
agg_sorted_kernel(const float* __restrict__ feature,
                  const unsigned* __restrict__ pairs,
                  const int* __restrict__ boff,
                  const float* __restrict__ W,
                  const float* __restrict__ bias,
                  float* __restrict__ out, int n_nodes) {
    __shared__ float Wt[64 * 65];      // Wt[k*65+o] = W[o*64+k]
    __shared__ unsigned short slist[CAP];
    __shared__ int cnt[64], offs[64], cur[64];

    int tid = threadIdx.x;
    int lane = tid & 63, w = tid >> 6;      // w in [0,16)
    for (int i = tid; i < 64 * 64; i += 1024) {
        int o = i >> 6, k = i & 63;
        Wt[k * 65 + o] = W[i];
    }

    int bkt = blockIdx.x;
    int e0 = boff[bkt], e1 = boff[bkt + 1];

    // wave w owns local nodes w, w+16, w+32, w+48
    float a[4] = {0.f, 0.f, 0.f, 0.f};

    for (int c0 = e0; c0 < e1; c0 += CAP) {
        int c1 = c0 + CAP; if (c1 > e1) c1 = e1;

        if (tid < 64) cnt[tid] = 0;
        __syncthreads();
        for (int i = c0 + tid; i < c1; i += 1024)
            atomicAdd(&cnt[pairs[i] >> 16], 1);
        __syncthreads();
        if (w == 0) {
            int v = cnt[lane];
            int x = v;
            for (int o = 1; o < 64; o <<= 1) {
                int y = __shfl_up(x, o, 64);
                if (lane >= o) x += y;
            }
            offs[lane] = x - v;
            cur[lane] = x - v;
        }
        __syncthreads();
        for (int i = c0 + tid; i < c1; i += 1024) {
            unsigned p = pairs[i];
            int pos = atomicAdd(&cur[p >> 16], 1);  // LDS atomic
            slist[pos] = (unsigned short)(p & 0xffffu);
        }
        __syncthreads();

#pragma unroll
        for (int q = 0; q < 4; ++q) {
            int ln = w + q * 16;
            int off = offs[ln], deg = cnt[ln];
            float acc0 = 0.f, acc1 = 0.f;
            for (int base = 0; base < deg; base += 64) {
                int m = deg - base; if (m > 64) m = 64;
                int sidx = (lane < m) ? (int)slist[off + base + lane] : 0;
                int j = 0;
                for (; j + 4 <= m; j += 4) {
                    int s0 = __shfl(sidx, j + 0, 64);
                    int s1 = __shfl(sidx, j + 1, 64);
                    int s2 = __shfl(sidx, j + 2, 64);
                    int s3 = __shfl(sidx, j + 3, 64);
                    float f0 = feature[s0 * D + lane];
                    float f1 = feature[s1 * D + lane];
                    float f2 = feature[s2 * D + lane];
                    float f3 = feature[s3 * D + lane];
                    acc0 += f0 + f1;
                    acc1 += f2 + f3;
                }
                for (; j < m; ++j) {
                    int s = __shfl(sidx, j, 64);
                    acc0 += feature[s * D + lane];
                }
            }
            a[q] += acc0 + acc1;
        }
        __syncthreads();   // slist/cnt reused next chunk
    }

    // epilogue: out[n] = b + a[q] @ W^T (shuffle-dot, no LDS round-trip for a)
    int n0 = bkt * 64;
#pragma unroll
    for (int q = 0; q < 4; ++q) {
        int n = n0 + w + q * 16;
        if (n < n_nodes) {
            float r = bias[lane];
#pragma unroll
            for (int k = 0; k < 64; ++k)
                r += __shfl(a[q], k, 64) * Wt[k * 65 + lane];
            out[n * D + lane] = r;
        }
    }
}

// ============================================================================
// Fallback paths (proven in earlier rounds)
// ============================================================================

__global__ void hist_kernel(const int* __restrict__ dst, int* __restrict__ counts, int n_edges) {
    int e = blockIdx.x * blockDim.x + threadIdx.x;
    if (e < n_edges) atomicAdd(&counts[dst[e]], 1);
}

__global__ void reduce_kernel(const int* __restrict__ counts, int* __restrict__ partials, int n_nodes) {
    __shared__ int wsums[4];
    int tid = threadIdx.x;
    int base = blockIdx.x * SCAN_CHUNK + tid * 4;
    int s = 0;
#pragma unroll
    for (int i = 0; i < 4; ++i) {
        int idx = base + i;
        if (idx < n_nodes) s += counts[idx];
    }
    for (int o = 32; o > 0; o >>= 1) s += __shfl_down(s, o, 64);
    int lane = tid & 63, wave = tid >> 6;
    if (lane == 0) wsums[wave] = s;
    __syncthreads();
    if (tid == 0) partials[blockIdx.x] = wsums[0] + wsums[1] + wsums[2] + wsums[3];
}

__global__ void scan_partials_kernel(const int* __restrict__ partials, int* __restrict__ pscan, int nblk) {
    int lane = threadIdx.x;
    int v = (lane < nblk) ? partials[lane] : 0;
    int orig = v;
    for (int o = 1; o < 64; o <<= 1) {
        int y = __shfl_up(v, o, 64);
        if (lane >= o) v += y;
    }
    if (lane < nblk) pscan[lane] = v - orig;
}

__global__ void scan_kernel(const int* __restrict__ counts, const int* __restrict__ pscan,
                            int* __restrict__ offsets, int* __restrict__ cursors, int n_nodes) {
    __shared__ int wsums[4];
    int tid = threadIdx.x;
    int base = blockIdx.x * SCAN_CHUNK + tid * 4;
    int c[4];
    int tsum = 0;
#pragma unroll
    for (int i = 0; i < 4; ++i) {
        int idx = base + i;
        c[i] = (idx < n_nodes) ? counts[idx] : 0;
        tsum += c[i];
    }
    int lane = tid & 63, wave = tid >> 6;
    int x = tsum;
    for (int o = 1; o < 64; o <<= 1) {
        int y = __shfl_up(x, o, 64);
        if (lane >= o) x += y;
    }
    if (lane == 63) wsums[wave] = x;
    __syncthreads();
    int wpre = 0;
    for (int w = 0; w < wave; ++w) wpre += wsums[w];
    int excl = (x - tsum) + wpre + pscan[blockIdx.x];
#pragma unroll
    for (int i = 0; i < 4; ++i) {
        int idx = base + i;
        if (idx < n_nodes) { offsets[idx] = excl; cursors[idx] = excl; }
        excl += c[i];
    }
}

__global__ void fill_kernel(const int* __restrict__ src, const int* __restrict__ dst,
                            int* __restrict__ cursors, int* __restrict__ elist, int n_edges) {
    int e = blockIdx.x * blockDim.x + threadIdx.x;
    if (e < n_edges) {
        int pos = atomicAdd(&cursors[dst[e]], 1);
        elist[pos] = src[e];
    }
}

__global__ void agg_linear_kernel(const float* __restrict__ feature,
                                  const int* __restrict__ elist,
                                  const int* __restrict__ offsets,
                                  const int* __restrict__ counts,
                                  const float* __restrict__ W,
                                  const float* __restrict__ b,
                                  float* __restrict__ out,
                                  int n_nodes, int total_waves) {
    __shared__ float Wt[64 * 65];
    int tid = threadIdx.x;
    for (int i = tid; i < 64 * 64; i += 256) {
        int o = i >> 6, k = i & 63;
        Wt[k * 65 + o] = W[i];
    }
    __syncthreads();
    int lane = tid & 63;
    int waveId = (blockIdx.x * 256 + tid) >> 6;
    float bias = b[lane];
    for (int n = waveId; n < n_nodes; n += total_waves) {
        int off = offsets[n];
        int deg = counts[n];
        float acc = 0.f;
        int j = 0;
        for (; j + 4 <= deg; j += 4) {
            int s0 = elist[off + j + 0];
            int s1 = elist[off + j + 1];
            int s2 = elist[off + j + 2];
            int s3 = elist[off + j + 3];
            acc += feature[s0 * D + lane] + feature[s1 * D + lane]
                 + feature[s2 * D + lane] + feature[s3 * D + lane];
        }
        for (; j < deg; ++j) acc += feature[elist[off + j] * D + lane];
        float r = bias;
#pragma unroll
        for (int k = 0; k < 64; ++k) r += __shfl(acc, k, 64) * Wt[k * 65 + lane];
        out[n * D + lane] = r;
    }
}

__global__ void gcn_scatter_kernel(const float* __restrict__ feature,
                                   const int* __restrict__ src,
                                   const int* __restrict__ dst,
                                   float* __restrict__ out,
                                   int n_edges) {
    int e = blockIdx.x * 4 + (threadIdx.x >> 6);
    int lane = threadIdx.x & 63;
    if (e < n_edges) atomicAdd(&out[dst[e] * D + lane], feature[src[e] * D + lane]);
}

__global__ void gcn_linear_kernel(float* __restrict__ out,
                                  const float* __restrict__ W,
                                  const float* __restrict__ b,
                                  int n_nodes) {
    __shared__ float Wt[64 * 65];
    int tid = threadIdx.x;
    for (int i = tid; i < 64 * 64; i += 256) {
        int o = i >> 6, k = i & 63;
        Wt[k * 65 + o] = W[i];
    }
    __syncthreads();
    int lane = tid & 63;
    int n = blockIdx.x * 4 + (tid >> 6);
    if (n >= n_nodes) return;
    float val = out[n * D + lane];
    float acc = b[lane];
#pragma unroll
    for (int k = 0; k < 64; ++k) acc += __shfl(val, k, 64) * Wt[k * 65 + lane];
    out[n * D + lane] = acc;
}

// ============================================================================

extern "C" void kernel_launch(void* const* d_in, const int* in_sizes, int n_in,
                              void* d_out, int out_size, void* d_ws, size_t ws_size,
                              hipStream_t stream) {
    const float* feature = (const float*)d_in[0];
    const int* src       = (const int*)d_in[1];
    const int* dst       = (const int*)d_in[2];
    const float* W       = (const float*)d_in[3];
    const float* b       = (const float*)d_in[4];
    float* out           = (float*)d_out;

    int n_edges = in_sizes[1];
    int n_nodes = in_sizes[0] / D;

    int nb = (n_nodes + 63) >> 6;                 // buckets of 64 nodes (782)
    int chunk = (n_edges + NBLK - 1) / NBLK;

    // ws (ints): cnt[nb*NBLK] | base[nb*NBLK] | btotal[nb] | boff[nb+1] | pairs[E]
    size_t needNew = ((size_t)2 * nb * NBLK + 2 * nb + 1 + (size_t)n_edges) * sizeof(int);

    if (n_nodes <= 65536 && nb <= NB_MAX && ws_size >= needNew) {
        int* cnt      = (int*)d_ws;
        int* base     = cnt + (size_t)nb * NBLK;
        int* btotal   = base + (size_t)nb * NBLK;
        int* boff     = btotal + nb;
        unsigned* pairs = (unsigned*)(boff + nb + 1);

        bhist_kernel<<<NBLK, 256, 0, stream>>>(dst, cnt, n_edges, nb, chunk);
        scan_cnt_kernel<<<nb, 256, 0, stream>>>(cnt, base, btotal);
        scan_buckets_kernel<<<1, 64, 0, stream>>>(btotal, boff, nb);
        scatter_kernel<<<NBLK, 256, 0, stream>>>(src, dst, base, boff, pairs,
                                                 n_edges, nb, chunk);
        agg_sorted_kernel<<<nb, 1024, 0, stream>>>(feature, pairs, boff, W, b, out, n_nodes);
        return;
    }

    // Tier B fallback (round-2 path)
    size_t needB = ((size_t)3 * n_nodes + 128 + (size_t)n_edges) * sizeof(int);
    int nblk_scan = (n_nodes + SCAN_CHUNK - 1) / SCAN_CHUNK;
    if (ws_size >= needB && nblk_scan <= 64) {
        int* counts   = (int*)d_ws;
        int* offsets  = counts + n_nodes;
        int* cursors  = offsets + n_nodes;
        int* partials = cursors + n_nodes;
        int* pscan    = partials + 64;
        int* elist    = pscan + 64;

        hipMemsetAsync(counts, 0, (size_t)n_nodes * sizeof(int), stream);
        hist_kernel<<<(n_edges + 255) / 256, 256, 0, stream>>>(dst, counts, n_edges);
        reduce_kernel<<<nblk_scan, 256, 0, stream>>>(counts, partials, n_nodes);
        scan_partials_kernel<<<1, 64, 0, stream>>>(partials, pscan, nblk_scan);
        scan_kernel<<<nblk_scan, 256, 0, stream>>>(counts, pscan, offsets, cursors, n_nodes);
        fill_kernel<<<(n_edges + 255) / 256, 256, 0, stream>>>(src, dst, cursors, elist, n_edges);
        agg_linear_kernel<<<3125, 256, 0, stream>>>(feature, elist, offsets, counts, W, b, out,
                                                    n_nodes, 3125 * 4);
        return;
    }

    // Last resort (round-1 path)
    hipMemsetAsync(d_out, 0, (size_t)out_size * sizeof(float), stream);
    gcn_scatter_kernel<<<(n_edges + 3) / 4, 256, 0, stream>>>(feature, src, dst, out, n_edges);
    gcn_linear_kernel<<<(n_nodes + 3) / 4, 256, 0, stream>>>(out, W, b, n_nodes);
}

// Round 6
// 169.951 us; speedup vs baseline: 3.9645x; 1.2218x over previous
//
#include <hip/hip_runtime.h>

#define D 64
#define SNB 64            // scatter/hist edge-chunk blocks
#define NBP 1024          // padded bucket count (nb <= NBP)
#define SCAP 20480        // scatter per-block LDS sort capacity (chunk must fit)
#define CAP 3072          // agg per-chunk edge capacity (bucket deg ~1600)
#define SCAN_CHUNK 1024

// ============================================================================
// Atomic-free bucket path. bucket = dst>>6 (64 nodes/bucket).
// pairs[pos] = (local_dst<<16) | src  (needs n_nodes <= 65536, nb <= 1024)
// ============================================================================

// Per-chunk bucket histogram; cnt laid out [blk][bucket] -> coalesced writes.
__global__ void __launch_bounds__(1024)
bhist64_kernel(const int* __restrict__ dst, int* __restrict__ cnt,
               int n_edges, int nb, int chunk) {
    __shared__ int hist[NBP];
    int blk = blockIdx.x, tid = threadIdx.x;
    for (int i = tid; i < NBP; i += 1024) hist[i] = 0;
    __syncthreads();
    int e0 = blk * chunk;
    int e1 = e0 + chunk; if (e1 > n_edges) e1 = n_edges;
    for (int e = e0 + tid; e < e1; e += 1024) atomicAdd(&hist[dst[e] >> 6], 1);
    __syncthreads();
    for (int i = tid; i < nb; i += 1024) cnt[blk * NBP + i] = hist[i];
}

// One 64-thread block per bucket: exclusive scan of its SNB block-counts.
__global__ void scan_cnt64_kernel(const int* __restrict__ cnt, int* __restrict__ base,
                                  int* __restrict__ btotal) {
    int bkt = blockIdx.x, lane = threadIdx.x;     // 64 threads == SNB
    int v = cnt[lane * NBP + bkt];
    int x = v;
    for (int o = 1; o < 64; o <<= 1) {
        int y = __shfl_up(x, o, 64);
        if (lane >= o) x += y;
    }
    base[lane * NBP + bkt] = x - v;
    if (lane == 63) btotal[bkt] = x;
}

// Single wave: exclusive scan of bucket totals -> boff[0..nb], boff[nb]=E.
__global__ void scan_buckets_kernel(const int* __restrict__ totals,
                                    int* __restrict__ boff, int nb) {
    int lane = threadIdx.x;
    int carry = 0;
    for (int s = 0; s < nb; s += 64) {
        int i = s + lane;
        int v = (i < nb) ? totals[i] : 0;
        int x = v;
        for (int o = 1; o < 64; o <<= 1) {
            int y = __shfl_up(x, o, 64);
            if (lane >= o) x += y;
        }
        if (i < nb) boff[i] = carry + x - v;
        carry += __shfl(x, 63, 64);
    }
    if (lane == 0) boff[nb] = carry;
}

// In-LDS counting sort of this block's chunk, then bucket-ordered write-out:
// global writes become ~25-word contiguous runs per bucket -> line-efficient.
__global__ void __launch_bounds__(1024)
scatter_sorted_kernel(const int* __restrict__ src, const int* __restrict__ dst,
                      const int* __restrict__ cnt, const int* __restrict__ base,
                      const int* __restrict__ boff, unsigned* __restrict__ pairs,
                      int n_edges, int nb, int chunk) {
    __shared__ unsigned sorted[SCAP];
    __shared__ int cur[NBP];
    __shared__ int dlt[NBP];     // global_pos = local_pos + dlt[bucket]
    __shared__ int wsum[16];

    int blk = blockIdx.x, tid = threadIdx.x;
    int lane = tid & 63, w = tid >> 6;

    // block-wide exclusive scan of this block's cnt row -> local offsets
    int v = (tid < nb) ? cnt[blk * NBP + tid] : 0;
    int x = v;
    for (int o = 1; o < 64; o <<= 1) {
        int y = __shfl_up(x, o, 64);
        if (lane >= o) x += y;
    }
    if (lane == 63) wsum[w] = x;
    __syncthreads();
    int pre = 0;
    for (int i = 0; i < w; ++i) pre += wsum[i];
    int excl = x - v + pre;
    if (tid < nb) {
        cur[tid] = excl;
        dlt[tid] = boff[tid] + base[blk * NBP + tid] - excl;
    }
    __syncthreads();

    int e0 = blk * chunk;
    int e1 = e0 + chunk; if (e1 > n_edges) e1 = n_edges;
    for (int e = e0 + tid; e < e1; e += 1024) {
        int d = dst[e];
        int pos = atomicAdd(&cur[d >> 6], 1);                 // LDS atomic
        sorted[pos] = ((unsigned)(d >> 6) << 22)
                    | ((unsigned)(d & 63) << 16) | (unsigned)src[e];
    }
    __syncthreads();

    int m = e1 - e0;
    for (int i = tid; i < m; i += 1024) {
        unsigned t = sorted[i];
        pairs[i + dlt[t >> 22]] = t & 0x3FFFFFu;
    }
}

// One 1024-thr block per bucket: in-LDS counting sort by local dst, quad-gather
// (lane L loads float4 of row s[L>>4] -> 4 edges per load), butterfly reduce,
// LDS-staged 64x64 linear epilogue with float4 stores.
__global__ void __launch_bounds__(1024, 8)
agg_quad_kernel(const float* __restrict__ feature,
                const unsigned* __restrict__ pairs,
                const int* __restrict__ boff,
                const float* __restrict__ W,
                const float* __restrict__ bias,
                float* __restrict__ out, int n_nodes) {
    __shared__ float4 Wt4[64 * 16];       // Wt4[k*16+oq].c = W[(4oq+c)*64 + k]
    __shared__ float  H[64 * 65];         // aggregated rows, padded
    __shared__ unsigned short slist[CAP];
    __shared__ int cnt[64], offs[64], cur[64];

    int tid = threadIdx.x;
    int lane = tid & 63, w = tid >> 6;    // 16 waves
    int g = lane >> 4, sl = lane & 15;    // subgroup / sub-lane

    {   // stage Wt4 (1024 threads == 64*16 entries)
        int k = tid >> 4, oq = tid & 15;
        float4 v;
        v.x = W[(4 * oq + 0) * 64 + k];
        v.y = W[(4 * oq + 1) * 64 + k];
        v.z = W[(4 * oq + 2) * 64 + k];
        v.w = W[(4 * oq + 3) * 64 + k];
        Wt4[k * 16 + oq] = v;
    }

    int bkt = blockIdx.x;
    int e0 = boff[bkt], e1 = boff[bkt + 1];

    // wave w owns local nodes w, w+16, w+32, w+48; float4 partial per subgroup
    float4 a4[4];
#pragma unroll
    for (int q = 0; q < 4; ++q) { a4[q].x = a4[q].y = a4[q].z = a4[q].w = 0.f; }

    for (int c0 = e0; c0 < e1; c0 += CAP) {
        int c1 = c0 + CAP; if (c1 > e1) c1 = e1;
        if (tid < 64) cnt[tid] = 0;
        __syncthreads();
        for (int i = c0 + tid; i < c1; i += 1024)
            atomicAdd(&cnt[pairs[i] >> 16], 1);
        __syncthreads();
        if (w == 0) {
            int v = cnt[lane];
            int x = v;
            for (int o = 1; o < 64; o <<= 1) {
                int y = __shfl_up(x, o, 64);
                if (lane >= o) x += y;
            }
            offs[lane] = x - v; cur[lane] = x - v;
        }
        __syncthreads();
        for (int i = c0 + tid; i < c1; i += 1024) {
            unsigned p = pairs[i];
            int pos = atomicAdd(&cur[p >> 16], 1);       // LDS atomic
            slist[pos] = (unsigned short)(p & 0xffffu);
        }
        __syncthreads();

#pragma unroll
        for (int q = 0; q < 4; ++q) {
            int ln = w + q * 16;
            int off = offs[ln], d = cnt[ln];
            float4 acc; acc.x = acc.y = acc.z = acc.w = 0.f;
            for (int j = 0; j < d; j += 4) {             // 4 edges per iter
                int i0 = j + g;
                int ic = (i0 < d - 1) ? i0 : (d - 1);    // clamped (valid addr)
                int s = slist[off + ic];
                const float4* fp = (const float4*)(feature + s * D + sl * 4);
                float4 f = *fp;
                float msk = (i0 < d) ? 1.f : 0.f;        // tail mask
                acc.x += f.x * msk; acc.y += f.y * msk;
                acc.z += f.z * msk; acc.w += f.w * msk;
            }
            a4[q].x += acc.x; a4[q].y += acc.y; a4[q].z += acc.z; a4[q].w += acc.w;
        }
        __syncthreads();   // slist/cnt reused next chunk
    }

    // butterfly reduce across 4 subgroups; stage h rows into H
#pragma unroll
    for (int q = 0; q < 4; ++q) {
        float4 h = a4[q];
        h.x += __shfl_xor(h.x, 16, 64);  h.y += __shfl_xor(h.y, 16, 64);
        h.z += __shfl_xor(h.z, 16, 64);  h.w += __shfl_xor(h.w, 16, 64);
        h.x += __shfl_xor(h.x, 32, 64);  h.y += __shfl_xor(h.y, 32, 64);
        h.z += __shfl_xor(h.z, 32, 64);  h.w += __shfl_xor(h.w, 32, 64);
        if (g == 0) {
            int ln = w + q * 16;
            H[ln * 65 + sl * 4 + 0] = h.x;
            H[ln * 65 + sl * 4 + 1] = h.y;
            H[ln * 65 + sl * 4 + 2] = h.z;
            H[ln * 65 + sl * 4 + 3] = h.w;
        }
    }
    __syncthreads();

    // epilogue GEMM: thread -> (node ln, output quad oq); coalesced f4 stores
    int ln = tid >> 4, oq = tid & 15;
    int n = bkt * 64 + ln;
    if (n < n_nodes) {
        float4 r = *(const float4*)(bias + oq * 4);
#pragma unroll
        for (int k = 0; k < 64; ++k) {
            float hk = H[ln * 65 + k];
            float4 wv = Wt4[k * 16 + oq];
            r.x += hk * wv.x; r.y += hk * wv.y;
            r.z += hk * wv.z; r.w += hk * wv.w;
        }
        *(float4*)(out + n * D + oq * 4) = r;
    }
}

// ============================================================================
// Fallback paths (proven in earlier rounds)
// ============================================================================

__global__ void hist_kernel(const int* __restrict__ dst, int* __restrict__ counts, int n_edges) {
    int e = blockIdx.x * blockDim.x + threadIdx.x;
    if (e < n_edges) atomicAdd(&counts[dst[e]], 1);
}

__global__ void reduce_kernel(const int* __restrict__ counts, int* __restrict__ partials, int n_nodes) {
    __shared__ int wsums[4];
    int tid = threadIdx.x;
    int base = blockIdx.x * SCAN_CHUNK + tid * 4;
    int s = 0;
#pragma unroll
    for (int i = 0; i < 4; ++i) {
        int idx = base + i;
        if (idx < n_nodes) s += counts[idx];
    }
    for (int o = 32; o > 0; o >>= 1) s += __shfl_down(s, o, 64);
    int lane = tid & 63, wave = tid >> 6;
    if (lane == 0) wsums[wave] = s;
    __syncthreads();
    if (tid == 0) partials[blockIdx.x] = wsums[0] + wsums[1] + wsums[2] + wsums[3];
}

__global__ void scan_partials_kernel(const int* __restrict__ partials, int* __restrict__ pscan, int nblk) {
    int lane = threadIdx.x;
    int v = (lane < nblk) ? partials[lane] : 0;
    int orig = v;
    for (int o = 1; o < 64; o <<= 1) {
        int y = __shfl_up(v, o, 64);
        if (lane >= o) v += y;
    }
    if (lane < nblk) pscan[lane] = v - orig;
}

__global__ void scan_kernel(const int* __restrict__ counts, const int* __restrict__ pscan,
                            int* __restrict__ offsets, int* __restrict__ cursors, int n_nodes) {
    __shared__ int wsums[4];
    int tid = threadIdx.x;
    int base = blockIdx.x * SCAN_CHUNK + tid * 4;
    int c[4];
    int tsum = 0;
#pragma unroll
    for (int i = 0; i < 4; ++i) {
        int idx = base + i;
        c[i] = (idx < n_nodes) ? counts[idx] : 0;
        tsum += c[i];
    }
    int lane = tid & 63, wave = tid >> 6;
    int x = tsum;
    for (int o = 1; o < 64; o <<= 1) {
        int y = __shfl_up(x, o, 64);
        if (lane >= o) x += y;
    }
    if (lane == 63) wsums[wave] = x;
    __syncthreads();
    int wpre = 0;
    for (int w = 0; w < wave; ++w) wpre += wsums[w];
    int excl = (x - tsum) + wpre + pscan[blockIdx.x];
#pragma unroll
    for (int i = 0; i < 4; ++i) {
        int idx = base + i;
        if (idx < n_nodes) { offsets[idx] = excl; cursors[idx] = excl; }
        excl += c[i];
    }
}

__global__ void fill_kernel(const int* __restrict__ src, const int* __restrict__ dst,
                            int* __restrict__ cursors, int* __restrict__ elist, int n_edges) {
    int e = blockIdx.x * blockDim.x + threadIdx.x;
    if (e < n_edges) {
        int pos = atomicAdd(&cursors[dst[e]], 1);
        elist[pos] = src[e];
    }
}

__global__ void agg_linear_kernel(const float* __restrict__ feature,
                                  const int* __restrict__ elist,
                                  const int* __restrict__ offsets,
                                  const int* __restrict__ counts,
                                  const float* __restrict__ W,
                                  const float* __restrict__ b,
                                  float* __restrict__ out,
                                  int n_nodes, int total_waves) {
    __shared__ float Wt[64 * 65];
    int tid = threadIdx.x;
    for (int i = tid; i < 64 * 64; i += 256) {
        int o = i >> 6, k = i & 63;
        Wt[k * 65 + o] = W[i];
    }
    __syncthreads();
    int lane = tid & 63;
    int waveId = (blockIdx.x * 256 + tid) >> 6;
    float bias = b[lane];
    for (int n = waveId; n < n_nodes; n += total_waves) {
        int off = offsets[n];
        int deg = counts[n];
        float acc = 0.f;
        int j = 0;
        for (; j + 4 <= deg; j += 4) {
            int s0 = elist[off + j + 0];
            int s1 = elist[off + j + 1];
            int s2 = elist[off + j + 2];
            int s3 = elist[off + j + 3];
            acc += feature[s0 * D + lane] + feature[s1 * D + lane]
                 + feature[s2 * D + lane] + feature[s3 * D + lane];
        }
        for (; j < deg; ++j) acc += feature[elist[off + j] * D + lane];
        float r = bias;
#pragma unroll
        for (int k = 0; k < 64; ++k) r += __shfl(acc, k, 64) * Wt[k * 65 + lane];
        out[n * D + lane] = r;
    }
}

__global__ void gcn_scatter_kernel(const float* __restrict__ feature,
                                   const int* __restrict__ src,
                                   const int* __restrict__ dst,
                                   float* __restrict__ out,
                                   int n_edges) {
    int e = blockIdx.x * 4 + (threadIdx.x >> 6);
    int lane = threadIdx.x & 63;
    if (e < n_edges) atomicAdd(&out[dst[e] * D + lane], feature[src[e] * D + lane]);
}

__global__ void gcn_linear_kernel(float* __restrict__ out,
                                  const float* __restrict__ W,
                                  const float* __restrict__ b,
                                  int n_nodes) {
    __shared__ float Wt[64 * 65];
    int tid = threadIdx.x;
    for (int i = tid; i < 64 * 64; i += 256) {
        int o = i >> 6, k = i & 63;
        Wt[k * 65 + o] = W[i];
    }
    __syncthreads();
    int lane = tid & 63;
    int n = blockIdx.x * 4 + (tid >> 6);
    if (n >= n_nodes) return;
    float val = out[n * D + lane];
    float acc = b[lane];
#pragma unroll
    for (int k = 0; k < 64; ++k) acc += __shfl(val, k, 64) * Wt[k * 65 + lane];
    out[n * D + lane] = acc;
}

// ============================================================================

extern "C" void kernel_launch(void* const* d_in, const int* in_sizes, int n_in,
                              void* d_out, int out_size, void* d_ws, size_t ws_size,
                              hipStream_t stream) {
    const float* feature = (const float*)d_in[0];
    const int* src       = (const int*)d_in[1];
    const int* dst       = (const int*)d_in[2];
    const float* W       = (const float*)d_in[3];
    const float* b       = (const float*)d_in[4];
    float* out           = (float*)d_out;

    int n_edges = in_sizes[1];
    int n_nodes = in_sizes[0] / D;

    int nb = (n_nodes + 63) >> 6;                 // 64-node buckets (782)
    int chunk = (n_edges + SNB - 1) / SNB;        // 19532 for E=1.25M

    // ws (ints): cnt[SNB*NBP] | base[SNB*NBP] | btotal[NBP] | boff[NBP+1] | pairs[E]
    size_t needNew = ((size_t)2 * SNB * NBP + 2 * NBP + 1 + (size_t)n_edges) * sizeof(int);

    if (n_nodes <= 65536 && nb <= NBP && chunk <= SCAP && ws_size >= needNew) {
        int* cnt        = (int*)d_ws;
        int* base       = cnt + (size_t)SNB * NBP;
        int* btotal     = base + (size_t)SNB * NBP;
        int* boff       = btotal + NBP;
        unsigned* pairs = (unsigned*)(boff + NBP + 1);

        bhist64_kernel<<<SNB, 1024, 0, stream>>>(dst, cnt, n_edges, nb, chunk);
        scan_cnt64_kernel<<<nb, 64, 0, stream>>>(cnt, base, btotal);
        scan_buckets_kernel<<<1, 64, 0, stream>>>(btotal, boff, nb);
        scatter_sorted_kernel<<<SNB, 1024, 0, stream>>>(src, dst, cnt, base, boff,
                                                        pairs, n_edges, nb, chunk);
        agg_quad_kernel<<<nb, 1024, 0, stream>>>(feature, pairs, boff, W, b, out, n_nodes);
        return;
    }

    // Tier B fallback (round-2 path)
    size_t needB = ((size_t)3 * n_nodes + 128 + (size_t)n_edges) * sizeof(int);
    int nblk_scan = (n_nodes + SCAN_CHUNK - 1) / SCAN_CHUNK;
    if (ws_size >= needB && nblk_scan <= 64) {
        int* counts   = (int*)d_ws;
        int* offsets  = counts + n_nodes;
        int* cursors  = offsets + n_nodes;
        int* partials = cursors + n_nodes;
        int* pscan    = partials + 64;
        int* elist    = pscan + 64;

        hipMemsetAsync(counts, 0, (size_t)n_nodes * sizeof(int), stream);
        hist_kernel<<<(n_edges + 255) / 256, 256, 0, stream>>>(dst, counts, n_edges);
        reduce_kernel<<<nblk_scan, 256, 0, stream>>>(counts, partials, n_nodes);
        scan_partials_kernel<<<1, 64, 0, stream>>>(partials, pscan, nblk_scan);
        scan_kernel<<<nblk_scan, 256, 0, stream>>>(counts, pscan, offsets, cursors, n_nodes);
        fill_kernel<<<(n_edges + 255) / 256, 256, 0, stream>>>(src, dst, cursors, elist, n_edges);
        agg_linear_kernel<<<3125, 256, 0, stream>>>(feature, elist, offsets, counts, W, b, out,
                                                    n_nodes, 3125 * 4);
        return;
    }

    // Last resort (round-1 path)
    hipMemsetAsync(d_out, 0, (size_t)out_size * sizeof(float), stream);
    gcn_scatter_kernel<<<(n_edges + 3) / 4, 256, 0, stream>>>(feature, src, dst, out, n_edges);
    gcn_linear_kernel<<<(n_nodes + 3) / 4, 256, 0, stream>>>(out, W, b, n_nodes);
}